// Round 4
// baseline (4521.015 us; speedup 1.0000x reference)
//
#include <hip/hip_runtime.h>
#include <hip/hip_bf16.h>
#include <stdint.h>

// Problem constants
#define B_    128
#define T_    1024
#define IN_   256
#define L_    1024
#define OUT_  256
#define KTOT  1280   // IN_ + L_

// Decomposition: 8 groups x 16 batches; each group = 32 WGs x 32 latent cols.
#define GROUPS 8
#define WPG    32
#define NB     16
#define NC     32
#define PAD_K  1288                       // 1280 + 8 bf16 pad
#define LDS_W_BYTES (NC * PAD_K * 2)      // 82432
#define RED_BYTES   (8 * 4 * 64 * 4)      // 8192
#define STILE_BYTES (16 * 32 * 2)         // 1024
#define LDS_TOTAL   (LDS_W_BYTES + RED_BYTES + STILE_BYTES)   // 91648

#define SENT      0x7F807F80u             // two bf16 +inf: tanh can never produce
#define SLOT      (B_ * L_)               // elements per ring slot (bf16)
#define RETRY_CAP 20000                   // safety valve: wrong-but-terminating

using short8 = __attribute__((ext_vector_type(8))) short;
using bf16x8 = __attribute__((ext_vector_type(8))) __bf16;
using f32x4  = __attribute__((ext_vector_type(4))) float;
using u32x4  = __attribute__((ext_vector_type(4))) unsigned;

__device__ __forceinline__ unsigned short f2b(float f) {   // fp32 -> bf16 RNE
  unsigned u = __builtin_bit_cast(unsigned, f);
  u += 0x7FFFu + ((u >> 16) & 1u);
  return (unsigned short)(u >> 16);
}
__device__ __forceinline__ float b2f(unsigned short h) {
  unsigned u = ((unsigned)h) << 16;
  return __builtin_bit_cast(float, u);
}
__device__ __forceinline__ float fast_tanh(float z) {
  z = fminf(fmaxf(z, -30.f), 30.f);
  float e2 = __expf(2.f * z);
  return __fdividef(e2 - 1.f, e2 + 1.f);
}
__device__ __forceinline__ int chunk_ok(short8 c) {
  u32x4 u = __builtin_bit_cast(u32x4, c);
  return (u[0] != SENT) & (u[1] != SENT) & (u[2] != SENT) & (u[3] != SENT);
}
// System-scope (sc0 sc1): proven-coherent across XCDs (Round 2 ran this correctly).
__device__ __forceinline__ void st_dw(unsigned int* p, unsigned int v) {
  asm volatile("global_store_dword %0, %1, off sc0 sc1" :: "v"(p), "v"(v) : "memory");
}
__device__ __forceinline__ void ld_x4(short8& d, const unsigned short* p) {
  asm volatile("global_load_dwordx4 %0, %1, off sc0 sc1" : "=v"(d) : "v"(p) : "memory");
}

__global__ void init_ws(unsigned int* ring_dw) {
  size_t i = (size_t)blockIdx.x * 256 + threadIdx.x;
  const size_t total = (size_t)4 * SLOT / 2;   // dwords in 4 slots
  for (size_t k = i; k < total; k += (size_t)256 * 256) ring_dw[k] = SENT;
}

__global__ __launch_bounds__(256, 1)
void rnn_persistent(const float* __restrict__ x, const float* __restrict__ Wlin,
                    unsigned short* __restrict__ ring)
{
  extern __shared__ char smem[];
  short* Wlds = (short*)smem;                                   // [NC][PAD_K] bf16
  float* red  = (float*)(smem + LDS_W_BYTES);
  unsigned short* stile = (unsigned short*)(smem + LDS_W_BYTES + RED_BYTES);

  const int tid = threadIdx.x;
  const int g   = blockIdx.x & 7;       // group (XCD locality heuristic only)
  const int w   = blockIdx.x >> 3;      // 0..31: col slice
  const int bb  = g * NB;
  const int cc  = w * NC;

  // ---- one-time: stage this WG's weight rows (bf16) into LDS ----
  for (int r = 0; r < NC; ++r) {
    const float* wrow = Wlin + (size_t)(cc + r) * KTOT;
    for (int k = tid; k < KTOT; k += 256)
      Wlds[r * PAD_K + k] = (short)f2b(wrow[k]);
  }
  __syncthreads();

  const int wv   = tid >> 6;            // wave 0..3 (K-split)
  const int l    = tid & 63;
  const int lrow = l & 15;              // M-row (A) / N-col (B) within tile
  const int lk   = (l >> 4) * 8;        // K offset within k-step
  const int prow = tid >> 4;            // publish/reset row 0..15
  const int pcol = tid & 15;            // publish/reset dword col 0..15

  for (int t = 0; t < T_; ++t) {
    unsigned short* hcur = ring + (size_t)(t & 3) * SLOT;         // h_t
    unsigned short* hnxt = ring + (size_t)((t + 1) & 3) * SLOT;   // h_{t+1}

    // ---- 1. fire-and-forget re-sentinel of slot (t-2) (== slot (t+2)&3).
    // Safe: h_{t-1} was validated during step t-1 => every WG finished step t-2
    // => every read of h_{t-2} drained. Drained by vmcnt(0) before our publish,
    // and peers only write h_{t+2} here after validating our h_{t+1}. ----
    {
      unsigned int* rp = (unsigned int*)(ring + (size_t)((t + 2) & 3) * SLOT
                                         + (size_t)(bb + prow) * L_ + cc) + pcol;
      st_dw(rp, SENT);
    }

    // ---- 2. issue h loads as early as possible (critical path) ----
    short8 hf[8];
    const unsigned short* hbase = hcur + (size_t)(bb + lrow) * L_ + wv * 32 + lk;
    if (t > 0) {
      #pragma unroll
      for (int j = 0; j < 8; ++j)
        ld_x4(hf[j], hbase + j * 128);
    }

    f32x4 acc0 = {0.f, 0.f, 0.f, 0.f};
    f32x4 acc1 = {0.f, 0.f, 0.f, 0.f};

    // ---- 3. x part (K 0..255) under the h-load flight ----
    #pragma unroll
    for (int j = 0; j < 2; ++j) {
      const int kk    = wv + 4 * j;
      const int kbase = kk * 32 + lk;
      const float* xp = x + ((size_t)(bb + lrow) * T_ + t) * IN_ + kbase;
      f32x4 x0 = *(const f32x4*)xp;
      f32x4 x1 = *(const f32x4*)(xp + 4);
      short8 a;
      a[0] = (short)f2b(x0[0]); a[1] = (short)f2b(x0[1]);
      a[2] = (short)f2b(x0[2]); a[3] = (short)f2b(x0[3]);
      a[4] = (short)f2b(x1[0]); a[5] = (short)f2b(x1[1]);
      a[6] = (short)f2b(x1[2]); a[7] = (short)f2b(x1[3]);
      short8 b0 = *(const short8*)&Wlds[lrow        * PAD_K + kbase];
      short8 b1 = *(const short8*)&Wlds[(lrow + 16) * PAD_K + kbase];
      acc0 = __builtin_amdgcn_mfma_f32_16x16x32_bf16(
               __builtin_bit_cast(bf16x8, a), __builtin_bit_cast(bf16x8, b0), acc0, 0, 0, 0);
      acc1 = __builtin_amdgcn_mfma_f32_16x16x32_bf16(
               __builtin_bit_cast(bf16x8, a), __builtin_bit_cast(bf16x8, b1), acc1, 0, 0, 0);
    }

    // ---- 4. validate h (sentinel check), bounded retry, then h MFMAs ----
    if (t > 0) {
      asm volatile("s_waitcnt vmcnt(0)" ::: "memory");
      __builtin_amdgcn_sched_barrier(0);

      bool okj[8] = {false, false, false, false, false, false, false, false};
      int remaining = 8, tries = 0;
      while (true) {
        #pragma unroll
        for (int j = 0; j < 8; ++j)
          if (!okj[j] && __all(chunk_ok(hf[j]))) { okj[j] = true; --remaining; }
        if (remaining == 0) break;
        if (++tries > RETRY_CAP) break;      // safety valve: never hang
        #pragma unroll
        for (int j = 0; j < 8; ++j)
          if (!okj[j]) ld_x4(hf[j], hbase + j * 128);
        asm volatile("s_waitcnt vmcnt(0)" ::: "memory");
        __builtin_amdgcn_sched_barrier(0);
      }

      #pragma unroll
      for (int j = 0; j < 8; ++j) {
        const int kbase = IN_ + wv * 32 + j * 128 + lk;
        short8 b0 = *(const short8*)&Wlds[lrow        * PAD_K + kbase];
        short8 b1 = *(const short8*)&Wlds[(lrow + 16) * PAD_K + kbase];
        acc0 = __builtin_amdgcn_mfma_f32_16x16x32_bf16(
                 __builtin_bit_cast(bf16x8, hf[j]), __builtin_bit_cast(bf16x8, b0), acc0, 0, 0, 0);
        acc1 = __builtin_amdgcn_mfma_f32_16x16x32_bf16(
                 __builtin_bit_cast(bf16x8, hf[j]), __builtin_bit_cast(bf16x8, b1), acc1, 0, 0, 0);
      }
    }

    // ---- 5. cross-wave K reduction via LDS, tanh, assemble tile ----
    #pragma unroll
    for (int j = 0; j < 4; ++j) {
      red[((wv * 2 + 0) * 4 + j) * 64 + l] = acc0[j];
      red[((wv * 2 + 1) * 4 + j) * 64 + l] = acc1[j];
    }
    __syncthreads();
    if (wv < 2) {
      const int tile = wv;
      #pragma unroll
      for (int j = 0; j < 4; ++j) {
        float s = red[((0 * 2 + tile) * 4 + j) * 64 + l]
                + red[((1 * 2 + tile) * 4 + j) * 64 + l]
                + red[((2 * 2 + tile) * 4 + j) * 64 + l]
                + red[((3 * 2 + tile) * 4 + j) * 64 + l];
        float hv = fast_tanh(s);
        // C/D layout: col = lane&15, row = (lane>>4)*4 + reg
        stile[((l >> 4) * 4 + j) * 32 + tile * 16 + (l & 15)] = f2b(hv);
      }
    }
    __syncthreads();

    // ---- 6. drain reset stores (issued ~whole step ago: ~free), then publish ----
    asm volatile("s_waitcnt vmcnt(0)" ::: "memory");
    {
      unsigned int v = ((const unsigned int*)stile)[tid];
      unsigned int* dp = (unsigned int*)(hnxt + (size_t)(bb + prow) * L_ + cc) + pcol;
      st_dw(dp, v);   // fire and forget — data self-validates at the consumer
    }
  }
}

__global__ __launch_bounds__(256)
void decode_kernel(const unsigned short* __restrict__ hfin,
                   const float* __restrict__ Wdec, const float* __restrict__ bdec,
                   float* __restrict__ out)
{
  __shared__ float hrow[L_];
  const int b = blockIdx.x, tid = threadIdx.x;
  for (int k = tid; k < L_; k += 256)
    hrow[k] = b2f(hfin[b * L_ + k]);
  __syncthreads();
  float s = bdec[tid];
  const float* wr = Wdec + (size_t)tid * L_;
  #pragma unroll 4
  for (int k = 0; k < L_; k += 4) {
    f32x4 wq = *(const f32x4*)(wr + k);
    s += hrow[k] * wq[0] + hrow[k+1] * wq[1] + hrow[k+2] * wq[2] + hrow[k+3] * wq[3];
  }
  out[b * OUT_ + tid] = fast_tanh(s);
}

extern "C" void kernel_launch(void* const* d_in, const int* in_sizes, int n_in,
                              void* d_out, int out_size, void* d_ws, size_t ws_size,
                              hipStream_t stream)
{
  const float* x    = (const float*)d_in[0];
  const float* Wlin = (const float*)d_in[1];
  const float* Wdec = (const float*)d_in[2];
  const float* bdec = (const float*)d_in[3];
  float* out = (float*)d_out;

  // ws layout: 4-slot h ring (4 x 128x1024 bf16 = 1 MB).
  unsigned short* ring = (unsigned short*)d_ws;

  hipFuncSetAttribute((const void*)rnn_persistent,
                      hipFuncAttributeMaxDynamicSharedMemorySize, LDS_TOTAL);

  hipLaunchKernelGGL(init_ws, dim3(256), dim3(256), 0, stream,
                     (unsigned int*)ring);
  hipLaunchKernelGGL(rnn_persistent, dim3(GROUPS * WPG), dim3(256), LDS_TOTAL, stream,
                     x, Wlin, ring);
  // final h = h_1024, in slot (1024 & 3) = 0
  hipLaunchKernelGGL(decode_kernel, dim3(B_), dim3(256), 0, stream,
                     ring, Wdec, bdec, out);
}

// Round 5
// 4504.747 us; speedup vs baseline: 1.0036x; 1.0036x over previous
//
#include <hip/hip_runtime.h>
#include <hip/hip_bf16.h>
#include <stdint.h>

// Problem constants
#define B_    128
#define T_    1024
#define IN_   256
#define L_    1024
#define OUT_  256
#define KTOT  1280   // IN_ + L_

// Decomposition: 8 groups x 16 batches; each group = 32 WGs x 32 latent cols.
#define GROUPS 8
#define WPG    32
#define NB     16
#define NC     32
#define PAD_K  1288                       // 1280 + 8 bf16 pad
#define LDS_W_BYTES (NC * PAD_K * 2)      // 82432
#define RED_BYTES   (8 * 4 * 64 * 4)      // 8192
#define STILE_BYTES (16 * 32 * 2)         // 1024
#define LDS_TOTAL   (LDS_W_BYTES + RED_BYTES + STILE_BYTES)   // 91648

#define SENT      0x7F807F80u             // two bf16 +inf: tanh can never produce
#define SLOT      (B_ * L_)               // elements per ring slot (bf16)
#define RETRY_CAP 20000                   // safety valve: wrong-but-terminating

using short8 = __attribute__((ext_vector_type(8))) short;
using bf16x8 = __attribute__((ext_vector_type(8))) __bf16;
using f32x4  = __attribute__((ext_vector_type(4))) float;
using u32x4  = __attribute__((ext_vector_type(4))) unsigned;

__device__ __forceinline__ unsigned short f2b(float f) {   // fp32 -> bf16 RNE
  unsigned u = __builtin_bit_cast(unsigned, f);
  u += 0x7FFFu + ((u >> 16) & 1u);
  return (unsigned short)(u >> 16);
}
__device__ __forceinline__ float b2f(unsigned short h) {
  unsigned u = ((unsigned)h) << 16;
  return __builtin_bit_cast(float, u);
}
__device__ __forceinline__ float fast_tanh(float z) {
  z = fminf(fmaxf(z, -30.f), 30.f);
  float e2 = __expf(2.f * z);
  return __fdividef(e2 - 1.f, e2 + 1.f);
}
__device__ __forceinline__ int chunk_ok(short8 c) {
  u32x4 u = __builtin_bit_cast(u32x4, c);
  return (u[0] != SENT) & (u[1] != SENT) & (u[2] != SENT) & (u[3] != SENT);
}
// System-scope (sc0 sc1): proven-coherent across XCDs (R2/R4 ran this correctly).
__device__ __forceinline__ void st_dw(unsigned int* p, unsigned int v) {
  asm volatile("global_store_dword %0, %1, off sc0 sc1" :: "v"(p), "v"(v) : "memory");
}
__device__ __forceinline__ void ld_x4(short8& d, const unsigned short* p) {
  asm volatile("global_load_dwordx4 %0, %1, off sc0 sc1" : "=v"(d) : "v"(p) : "memory");
}

__global__ void init_ws(unsigned int* ring_dw) {
  size_t i = (size_t)blockIdx.x * 256 + threadIdx.x;
  const size_t total = (size_t)4 * SLOT / 2;   // dwords in 4 slots
  for (size_t k = i; k < total; k += (size_t)256 * 256) ring_dw[k] = SENT;
}

__global__ __launch_bounds__(256, 1)
void rnn_persistent(const float* __restrict__ x, const float* __restrict__ Wlin,
                    unsigned short* __restrict__ ring)
{
  extern __shared__ char smem[];
  short* Wlds = (short*)smem;                                   // [NC][PAD_K] bf16
  float* red  = (float*)(smem + LDS_W_BYTES);
  unsigned short* stile = (unsigned short*)(smem + LDS_W_BYTES + RED_BYTES);

  const int tid = threadIdx.x;
  const int g   = blockIdx.x & 7;       // group (XCD locality heuristic only)
  const int w   = blockIdx.x >> 3;      // 0..31: col slice
  const int bb  = g * NB;
  const int cc  = w * NC;

  // ---- one-time: stage this WG's weight rows (bf16) into LDS ----
  for (int r = 0; r < NC; ++r) {
    const float* wrow = Wlin + (size_t)(cc + r) * KTOT;
    for (int k = tid; k < KTOT; k += 256)
      Wlds[r * PAD_K + k] = (short)f2b(wrow[k]);
  }
  __syncthreads();

  const int wv   = tid >> 6;            // wave 0..3 (K-split)
  const int l    = tid & 63;
  const int lrow = l & 15;              // M-row (A) / N-col (B) within tile
  const int lk   = (l >> 4) * 8;        // K offset within k-step
  const int prow = tid >> 4;            // publish/reset row 0..15
  const int pcol = tid & 15;            // publish/reset dword col 0..15

  for (int t = 0; t < T_; ++t) {
    unsigned short* hcur = ring + (size_t)(t & 3) * SLOT;         // h_t
    unsigned short* hnxt = ring + (size_t)((t + 1) & 3) * SLOT;   // h_{t+1}

    // ---- 1. issue h loads FIRST: nothing store-shaped ahead of them in vmcnt ----
    short8 hf[8];
    const unsigned short* hbase = hcur + (size_t)(bb + lrow) * L_ + wv * 32 + lk;
    if (t > 0) {
      #pragma unroll
      for (int j = 0; j < 8; ++j)
        ld_x4(hf[j], hbase + j * 128);
    }

    f32x4 acc0 = {0.f, 0.f, 0.f, 0.f};
    f32x4 acc1 = {0.f, 0.f, 0.f, 0.f};

    // ---- 2. x part (K 0..255) under the h-load flight ----
    #pragma unroll
    for (int j = 0; j < 2; ++j) {
      const int kk    = wv + 4 * j;
      const int kbase = kk * 32 + lk;
      const float* xp = x + ((size_t)(bb + lrow) * T_ + t) * IN_ + kbase;
      f32x4 x0 = *(const f32x4*)xp;
      f32x4 x1 = *(const f32x4*)(xp + 4);
      short8 a;
      a[0] = (short)f2b(x0[0]); a[1] = (short)f2b(x0[1]);
      a[2] = (short)f2b(x0[2]); a[3] = (short)f2b(x0[3]);
      a[4] = (short)f2b(x1[0]); a[5] = (short)f2b(x1[1]);
      a[6] = (short)f2b(x1[2]); a[7] = (short)f2b(x1[3]);
      short8 b0 = *(const short8*)&Wlds[lrow        * PAD_K + kbase];
      short8 b1 = *(const short8*)&Wlds[(lrow + 16) * PAD_K + kbase];
      acc0 = __builtin_amdgcn_mfma_f32_16x16x32_bf16(
               __builtin_bit_cast(bf16x8, a), __builtin_bit_cast(bf16x8, b0), acc0, 0, 0, 0);
      acc1 = __builtin_amdgcn_mfma_f32_16x16x32_bf16(
               __builtin_bit_cast(bf16x8, a), __builtin_bit_cast(bf16x8, b1), acc1, 0, 0, 0);
    }

    // ---- 3. validate h (sentinel check), bounded retry w/ backoff ----
    if (t > 0) {
      asm volatile("s_waitcnt vmcnt(0)" ::: "memory");
      __builtin_amdgcn_sched_barrier(0);

      bool okj[8] = {false, false, false, false, false, false, false, false};
      int remaining = 8, tries = 0;
      while (true) {
        #pragma unroll
        for (int j = 0; j < 8; ++j)
          if (!okj[j] && __all(chunk_ok(hf[j]))) { okj[j] = true; --remaining; }
        if (remaining == 0) break;
        if (++tries > RETRY_CAP) break;      // safety valve: never hang
        if (tries >= 2) __builtin_amdgcn_s_sleep(2);   // backoff: tame spin traffic
        #pragma unroll
        for (int j = 0; j < 8; ++j)
          if (!okj[j]) ld_x4(hf[j], hbase + j * 128);
        asm volatile("s_waitcnt vmcnt(0)" ::: "memory");
        __builtin_amdgcn_sched_barrier(0);
      }
    }

    // ---- 4. fire-and-forget re-sentinel of slot (t-2) (== slot (t+2)&3).
    // Placed AFTER validation so it never poisons the validation vmcnt(0).
    // Safety: only WE ever write this region; our pre-publish vmcnt(0) (step 6)
    // drains it before the h_{t+1} publish issues, and peers first read this
    // slot (expecting h_{t+2}) only after validating our h_{t+1}. ----
    {
      unsigned int* rp = (unsigned int*)(ring + (size_t)((t + 2) & 3) * SLOT
                                         + (size_t)(bb + prow) * L_ + cc) + pcol;
      st_dw(rp, SENT);
    }

    // ---- 5. h MFMAs, then cross-wave K reduction, tanh, assemble tile ----
    if (t > 0) {
      #pragma unroll
      for (int j = 0; j < 8; ++j) {
        const int kbase = IN_ + wv * 32 + j * 128 + lk;
        short8 b0 = *(const short8*)&Wlds[lrow        * PAD_K + kbase];
        short8 b1 = *(const short8*)&Wlds[(lrow + 16) * PAD_K + kbase];
        acc0 = __builtin_amdgcn_mfma_f32_16x16x32_bf16(
                 __builtin_bit_cast(bf16x8, hf[j]), __builtin_bit_cast(bf16x8, b0), acc0, 0, 0, 0);
        acc1 = __builtin_amdgcn_mfma_f32_16x16x32_bf16(
                 __builtin_bit_cast(bf16x8, hf[j]), __builtin_bit_cast(bf16x8, b1), acc1, 0, 0, 0);
      }
    }

    #pragma unroll
    for (int j = 0; j < 4; ++j) {
      red[((wv * 2 + 0) * 4 + j) * 64 + l] = acc0[j];
      red[((wv * 2 + 1) * 4 + j) * 64 + l] = acc1[j];
    }
    __syncthreads();
    if (wv < 2) {
      const int tile = wv;
      #pragma unroll
      for (int j = 0; j < 4; ++j) {
        float s = red[((0 * 2 + tile) * 4 + j) * 64 + l]
                + red[((1 * 2 + tile) * 4 + j) * 64 + l]
                + red[((2 * 2 + tile) * 4 + j) * 64 + l]
                + red[((3 * 2 + tile) * 4 + j) * 64 + l];
        float hv = fast_tanh(s);
        // C/D layout: col = lane&15, row = (lane>>4)*4 + reg
        stile[((l >> 4) * 4 + j) * 32 + tile * 16 + (l & 15)] = f2b(hv);
      }
    }
    __syncthreads();

    // ---- 6. drain reset stores (issued ~compute-time ago: cheap), then publish ----
    asm volatile("s_waitcnt vmcnt(0)" ::: "memory");
    {
      unsigned int v = ((const unsigned int*)stile)[tid];
      unsigned int* dp = (unsigned int*)(hnxt + (size_t)(bb + prow) * L_ + cc) + pcol;
      st_dw(dp, v);   // fire and forget — data self-validates at the consumer
    }
  }
}

__global__ __launch_bounds__(256)
void decode_kernel(const unsigned short* __restrict__ hfin,
                   const float* __restrict__ Wdec, const float* __restrict__ bdec,
                   float* __restrict__ out)
{
  __shared__ float hrow[L_];
  const int b = blockIdx.x, tid = threadIdx.x;
  for (int k = tid; k < L_; k += 256)
    hrow[k] = b2f(hfin[b * L_ + k]);
  __syncthreads();
  float s = bdec[tid];
  const float* wr = Wdec + (size_t)tid * L_;
  #pragma unroll 4
  for (int k = 0; k < L_; k += 4) {
    f32x4 wq = *(const f32x4*)(wr + k);
    s += hrow[k] * wq[0] + hrow[k+1] * wq[1] + hrow[k+2] * wq[2] + hrow[k+3] * wq[3];
  }
  out[b * OUT_ + tid] = fast_tanh(s);
}

extern "C" void kernel_launch(void* const* d_in, const int* in_sizes, int n_in,
                              void* d_out, int out_size, void* d_ws, size_t ws_size,
                              hipStream_t stream)
{
  const float* x    = (const float*)d_in[0];
  const float* Wlin = (const float*)d_in[1];
  const float* Wdec = (const float*)d_in[2];
  const float* bdec = (const float*)d_in[3];
  float* out = (float*)d_out;

  // ws layout: 4-slot h ring (4 x 128x1024 bf16 = 1 MB).
  unsigned short* ring = (unsigned short*)d_ws;

  hipFuncSetAttribute((const void*)rnn_persistent,
                      hipFuncAttributeMaxDynamicSharedMemorySize, LDS_TOTAL);

  hipLaunchKernelGGL(init_ws, dim3(256), dim3(256), 0, stream,
                     (unsigned int*)ring);
  hipLaunchKernelGGL(rnn_persistent, dim3(GROUPS * WPG), dim3(256), LDS_TOTAL, stream,
                     x, Wlin, ring);
  // final h = h_1024, in slot (1024 & 3) = 0
  hipLaunchKernelGGL(decode_kernel, dim3(B_), dim3(256), 0, stream,
                     ring, Wdec, bdec, out);
}

// Round 6
// 4127.452 us; speedup vs baseline: 1.0954x; 1.0914x over previous
//
#include <hip/hip_runtime.h>
#include <hip/hip_bf16.h>
#include <stdint.h>

// Problem constants
#define B_    128
#define T_    1024
#define IN_   256
#define L_    1024
#define OUT_  256
#define KTOT  1280   // IN_ + L_

// Decomposition: 8 groups x 16 WGs; each WG: 16 batches x 64 latent cols.
// All-to-all degree 16 (was 32); system-scope h traffic 4 MB/step (was 8).
#define GROUPS 8
#define WPG    16
#define NB     16
#define NC     64
#define PADW   1032                        // 1024 + 8 bf16 pad (16B skew/row)
#define LDS_W_BYTES (NC * PADW * 2)        // 132096: Wh slice
#define RED_BYTES   (4 * 4 * 4 * 64 * 4)   // 16384: [wave][tile][reg][lane] f32
#define LDS_TOTAL   (LDS_W_BYTES + RED_BYTES)  // 148480 < 160K

using short8 = __attribute__((ext_vector_type(8))) short;
using bf16x8 = __attribute__((ext_vector_type(8))) __bf16;
using f32x4  = __attribute__((ext_vector_type(4))) float;

__device__ __forceinline__ unsigned short f2b(float f) {   // fp32 -> bf16 RNE
  unsigned u = __builtin_bit_cast(unsigned, f);
  u += 0x7FFFu + ((u >> 16) & 1u);
  return (unsigned short)(u >> 16);
}
__device__ __forceinline__ float b2f(unsigned short h) {
  unsigned u = ((unsigned)h) << 16;
  return __builtin_bit_cast(float, u);
}
__device__ __forceinline__ float fast_tanh(float z) {
  z = fminf(fmaxf(z, -30.f), 30.f);
  float e2 = __expf(2.f * z);
  return __fdividef(e2 - 1.f, e2 + 1.f);
}
// System-scope data movement (proven coherent cross-XCD in R2/R4/R5).
__device__ __forceinline__ void st_us(unsigned short* p, unsigned short v) {
  asm volatile("global_store_short %0, %1, off sc0 sc1" :: "v"(p), "v"(v) : "memory");
}
__device__ __forceinline__ void ld_x4(short8& d, const unsigned short* p) {
  asm volatile("global_load_dwordx4 %0, %1, off sc0 sc1" : "=v"(d) : "v"(p) : "memory");
}
__device__ __forceinline__ short8 cvt8(f32x4 a, f32x4 b) {
  short8 v;
  v[0] = (short)f2b(a[0]); v[1] = (short)f2b(a[1]);
  v[2] = (short)f2b(a[2]); v[3] = (short)f2b(a[3]);
  v[4] = (short)f2b(b[0]); v[5] = (short)f2b(b[1]);
  v[6] = (short)f2b(b[2]); v[7] = (short)f2b(b[3]);
  return v;
}

__global__ __launch_bounds__(256, 1)
void rnn_persistent(const float* __restrict__ x, const float* __restrict__ Wlin,
                    unsigned short* __restrict__ h0buf, unsigned short* __restrict__ h1buf,
                    unsigned int* __restrict__ flags)
{
  extern __shared__ char smem[];
  short* Wlds = (short*)smem;                       // [NC][PADW] bf16 (Wh slice)
  float* red  = (float*)(smem + LDS_W_BYTES);       // K-split reduce buffer

  const int tid = threadIdx.x;
  const int g   = blockIdx.x & 7;       // group (XCD heuristic only; correctness-free)
  const int w   = blockIdx.x >> 3;      // 0..15: which 64-col slice
  const int bb  = g * NB;
  const int cc  = w * NC;

  // ---- one-time: stage Wh rows (h-part of Wlin) into LDS ----
  for (int r = 0; r < NC; ++r) {
    const float* wrow = Wlin + (size_t)(cc + r) * KTOT + IN_;
    for (int k = tid; k < L_; k += 256)
      Wlds[r * PADW + k] = (short)f2b(wrow[k]);
  }

  const int wv  = tid >> 6;             // wave 0..3 = K-quarter owner
  const int l   = tid & 63;
  const int lr  = l & 15;               // A-row / B-col within 16x16 tile
  const int lk8 = (l >> 4) * 8;         // K sub-offset within a k-step

  // ---- one-time: stage Wx fragments into REGISTERS (x-part folds into K-reduce) ----
  // wave wv owns x-K range [wv*64, wv*64+64): 4 N-tiles x 2 k-steps.
  short8 wx[4][2];
  #pragma unroll
  for (int nt = 0; nt < 4; ++nt) {
    #pragma unroll
    for (int ks = 0; ks < 2; ++ks) {
      const float* wp = Wlin + (size_t)(cc + nt * 16 + lr) * KTOT + wv * 64 + ks * 32 + lk8;
      wx[nt][ks] = cvt8(*(const f32x4*)wp, *(const f32x4*)(wp + 4));
    }
  }
  __syncthreads();

  unsigned int* myflag = flags + (size_t)(g * WPG + w) * 16;   // 64 B apart

  for (int t = 0; t < T_; ++t) {
    const unsigned short* hcur = (t & 1) ? h1buf : h0buf;      // h_t
    unsigned short*       hnxt = (t & 1) ? h0buf : h1buf;      // h_{t+1}

    f32x4 acc[4] = {{0,0,0,0},{0,0,0,0},{0,0,0,0},{0,0,0,0}};

    // ---- x part: off critical path (producers not done yet in steady state) ----
    #pragma unroll
    for (int ks = 0; ks < 2; ++ks) {
      const float* xp = x + ((size_t)(bb + lr) * T_ + t) * IN_ + wv * 64 + ks * 32 + lk8;
      short8 a = cvt8(*(const f32x4*)xp, *(const f32x4*)(xp + 4));
      #pragma unroll
      for (int nt = 0; nt < 4; ++nt)
        acc[nt] = __builtin_amdgcn_mfma_f32_16x16x32_bf16(
                    __builtin_bit_cast(bf16x8, a), __builtin_bit_cast(bf16x8, wx[nt][ks]),
                    acc[nt], 0, 0, 0);
    }

    // ---- h part: incremental per-producer consumption (wave wv needs only
    // producers 4wv..4wv+3, whose col-blocks are its K-range). ----
    if (t > 0) {
      const unsigned short* hrow = hcur + (size_t)(bb + lr) * L_;
      short8 hb[4][2];
      unsigned pending = 0xFu;
      while (pending) {
        unsigned fv = 0;
        if (l < 4)
          fv = __hip_atomic_load(flags + (size_t)(g * WPG + 4 * wv + l) * 16,
                                 __ATOMIC_RELAXED, __HIP_MEMORY_SCOPE_AGENT);
        unsigned avail = (unsigned)__ballot(l < 4 && fv >= (unsigned)t) & pending;
        if (avail) {
          #pragma unroll
          for (int p = 0; p < 4; ++p)
            if (avail & (1u << p)) {
              ld_x4(hb[p][0], hrow + (4 * wv + p) * 64 + lk8);
              ld_x4(hb[p][1], hrow + (4 * wv + p) * 64 + 32 + lk8);
            }
          asm volatile("s_waitcnt vmcnt(0)" ::: "memory");
          __builtin_amdgcn_sched_barrier(0);
          #pragma unroll
          for (int p = 0; p < 4; ++p)
            if (avail & (1u << p)) {
              #pragma unroll
              for (int ks = 0; ks < 2; ++ks) {
                const int kb = (4 * wv + p) * 64 + ks * 32 + lk8;
                #pragma unroll
                for (int nt = 0; nt < 4; ++nt) {
                  short8 bf = *(const short8*)&Wlds[(nt * 16 + lr) * PADW + kb];
                  acc[nt] = __builtin_amdgcn_mfma_f32_16x16x32_bf16(
                              __builtin_bit_cast(bf16x8, hb[p][ks]),
                              __builtin_bit_cast(bf16x8, bf), acc[nt], 0, 0, 0);
                }
              }
            }
          pending &= ~avail;
        } else {
          __builtin_amdgcn_s_sleep(1);
        }
      }
    }

    // ---- cross-wave K reduction (4-way) via LDS ----
    #pragma unroll
    for (int nt = 0; nt < 4; ++nt)
      #pragma unroll
      for (int j = 0; j < 4; ++j)
        red[((wv * 4 + nt) * 4 + j) * 64 + l] = acc[nt][j];
    __syncthreads();

    // ---- finalize: wave wv owns N-tile wv; tanh; direct system-scope publish ----
    #pragma unroll
    for (int j = 0; j < 4; ++j) {
      float s = red[((0 * 4 + wv) * 4 + j) * 64 + l]
              + red[((1 * 4 + wv) * 4 + j) * 64 + l]
              + red[((2 * 4 + wv) * 4 + j) * 64 + l]
              + red[((3 * 4 + wv) * 4 + j) * 64 + l];
      float hv = fast_tanh(s);
      // C/D layout (verified): col = lane&15, row = (lane>>4)*4 + reg
      st_us(hnxt + (size_t)(bb + (l >> 4) * 4 + j) * L_ + cc + wv * 16 + lr, f2b(hv));
    }

    // ---- drain publish (and consumed loads), then raise monotonic flag ----
    asm volatile("s_waitcnt vmcnt(0)" ::: "memory");
    __syncthreads();
    if (tid == 0)
      __hip_atomic_store(myflag, (unsigned)(t + 1), __ATOMIC_RELAXED, __HIP_MEMORY_SCOPE_AGENT);
  }
}

__global__ __launch_bounds__(256)
void decode_kernel(const unsigned short* __restrict__ hfin,
                   const float* __restrict__ Wdec, const float* __restrict__ bdec,
                   float* __restrict__ out)
{
  __shared__ float hrow[L_];
  const int b = blockIdx.x, tid = threadIdx.x;
  for (int k = tid; k < L_; k += 256)
    hrow[k] = b2f(hfin[b * L_ + k]);
  __syncthreads();
  float s = bdec[tid];
  const float* wr = Wdec + (size_t)tid * L_;
  #pragma unroll 4
  for (int k = 0; k < L_; k += 4) {
    f32x4 wq = *(const f32x4*)(wr + k);
    s += hrow[k] * wq[0] + hrow[k+1] * wq[1] + hrow[k+2] * wq[2] + hrow[k+3] * wq[3];
  }
  out[b * OUT_ + tid] = fast_tanh(s);
}

extern "C" void kernel_launch(void* const* d_in, const int* in_sizes, int n_in,
                              void* d_out, int out_size, void* d_ws, size_t ws_size,
                              hipStream_t stream)
{
  const float* x    = (const float*)d_in[0];
  const float* Wlin = (const float*)d_in[1];
  const float* Wdec = (const float*)d_in[2];
  const float* bdec = (const float*)d_in[3];
  float* out = (float*)d_out;

  // ws layout: h double buffer (2 x 128x1024 bf16 = 512 KB) + flags (8 KB).
  unsigned short* h0 = (unsigned short*)d_ws;
  unsigned short* h1 = h0 + (size_t)B_ * L_;
  unsigned int* flags = (unsigned int*)((char*)d_ws + (size_t)2 * B_ * L_ * 2);

  hipMemsetAsync(flags, 0, (size_t)GROUPS * WPG * 16 * sizeof(unsigned int), stream);

  hipFuncSetAttribute((const void*)rnn_persistent,
                      hipFuncAttributeMaxDynamicSharedMemorySize, LDS_TOTAL);

  hipLaunchKernelGGL(rnn_persistent, dim3(GROUPS * WPG), dim3(256), LDS_TOTAL, stream,
                     x, Wlin, h0, h1, flags);
  // final h = h_1024, parity (1024 & 1) = 0 -> h0
  hipLaunchKernelGGL(decode_kernel, dim3(B_), dim3(256), 0, stream,
                     h0, Wdec, bdec, out);
}

// Round 7
// 3295.423 us; speedup vs baseline: 1.3719x; 1.2525x over previous
//
#include <hip/hip_runtime.h>
#include <hip/hip_bf16.h>
#include <stdint.h>

// Problem constants
#define B_    128
#define T_    1024
#define IN_   256
#define L_    1024
#define OUT_  256
#define KTOT  1280   // IN_ + L_

// Decomposition: 8 groups x 16 batches; each group = 32 WGs x 32 latent cols.
// R7 = R2 byte-identical structure; ONLY the cache-scope bits on raw h data ops
// changed: stores sc0 sc1 -> sc1 (agent), loads sc0 sc1 -> sc1 nt.
#define GROUPS 8
#define WPG    32
#define NB     16
#define NC     32
#define PAD_K  1288                       // 1280 + 8 bf16 pad
#define LDS_W_BYTES (NC * PAD_K * 2)      // 82432
#define RED_BYTES   (8 * 4 * 64 * 4)      // 8192
#define STILE_BYTES (16 * 32 * 2)         // 1024
#define LDS_TOTAL   (LDS_W_BYTES + RED_BYTES + STILE_BYTES)   // 91648

using short8 = __attribute__((ext_vector_type(8))) short;
using bf16x8 = __attribute__((ext_vector_type(8))) __bf16;
using f32x4  = __attribute__((ext_vector_type(4))) float;

__device__ __forceinline__ unsigned short f2b(float f) {   // fp32 -> bf16 RNE
  unsigned u = __builtin_bit_cast(unsigned, f);
  u += 0x7FFFu + ((u >> 16) & 1u);
  return (unsigned short)(u >> 16);
}
__device__ __forceinline__ float b2f(unsigned short h) {
  unsigned u = ((unsigned)h) << 16;
  return __builtin_bit_cast(float, u);
}
__device__ __forceinline__ float fast_tanh(float z) {
  z = fminf(fmaxf(z, -30.f), 30.f);
  float e2 = __expf(2.f * z);
  return __fdividef(e2 - 1.f, e2 + 1.f);
}

// AGENT-scope data movement (sc1). Model: {sc0,sc1} is a scope field; sc1 =
// agent/device (coherence at IF/L3, cheaper than system sc0+sc1). Evidence:
// __hip_atomic AGENT flags (R2) are coherent cross-XCD and compile to sc1-class
// ops. 'nt' on loads prevents any stale L1/L2 retention of ring lines.
__device__ __forceinline__ void st_dw(unsigned int* p, unsigned int v) {
  asm volatile("global_store_dword %0, %1, off sc1" :: "v"(p), "v"(v) : "memory");
}
__device__ __forceinline__ void ld_x4(short8& d, const unsigned short* p) {
  asm volatile("global_load_dwordx4 %0, %1, off sc1 nt" : "=v"(d) : "v"(p) : "memory");
}

__global__ __launch_bounds__(256, 1)
void rnn_persistent(const float* __restrict__ x, const float* __restrict__ Wlin,
                    unsigned short* __restrict__ h0buf, unsigned short* __restrict__ h1buf,
                    unsigned int* __restrict__ flags)
{
  extern __shared__ char smem[];
  short* Wlds = (short*)smem;                                   // [NC][PAD_K] bf16
  float* red  = (float*)(smem + LDS_W_BYTES);
  unsigned short* stile = (unsigned short*)(smem + LDS_W_BYTES + RED_BYTES); // [16][32]

  const int tid = threadIdx.x;
  const int g   = blockIdx.x & 7;       // group (XCD locality heuristic only)
  const int w   = blockIdx.x >> 3;      // 0..31: col slice
  const int bb  = g * NB;
  const int cc  = w * NC;
  unsigned int* myflag = flags + (size_t)(g * WPG + w) * 16;    // 64 B apart

  // ---- one-time: stage this WG's weight rows (bf16) into LDS ----
  for (int r = 0; r < NC; ++r) {
    const float* wrow = Wlin + (size_t)(cc + r) * KTOT;
    for (int k = tid; k < KTOT; k += 256)
      Wlds[r * PAD_K + k] = (short)f2b(wrow[k]);
  }
  __syncthreads();

  const int wv   = tid >> 6;            // wave 0..3 (K-split)
  const int l    = tid & 63;
  const int lrow = l & 15;              // M-row (A) / N-col (B) within tile
  const int lk   = (l >> 4) * 8;        // K offset within k-step

  for (int t = 0; t < T_; ++t) {
    const unsigned short* hcur = (t & 1) ? h1buf : h0buf;
    unsigned short*       hnxt = (t & 1) ? h0buf : h1buf;

    f32x4 acc0 = {0.f, 0.f, 0.f, 0.f};
    f32x4 acc1 = {0.f, 0.f, 0.f, 0.f};

    // ---- x part (K 0..255): normal cached loads, off critical path ----
    #pragma unroll
    for (int j = 0; j < 2; ++j) {
      const int kk    = wv + 4 * j;
      const int kbase = kk * 32 + lk;
      const float* xp = x + ((size_t)(bb + lrow) * T_ + t) * IN_ + kbase;
      f32x4 x0 = *(const f32x4*)xp;
      f32x4 x1 = *(const f32x4*)(xp + 4);
      short8 a;
      a[0] = (short)f2b(x0[0]); a[1] = (short)f2b(x0[1]);
      a[2] = (short)f2b(x0[2]); a[3] = (short)f2b(x0[3]);
      a[4] = (short)f2b(x1[0]); a[5] = (short)f2b(x1[1]);
      a[6] = (short)f2b(x1[2]); a[7] = (short)f2b(x1[3]);
      short8 b0 = *(const short8*)&Wlds[lrow        * PAD_K + kbase];
      short8 b1 = *(const short8*)&Wlds[(lrow + 16) * PAD_K + kbase];
      acc0 = __builtin_amdgcn_mfma_f32_16x16x32_bf16(
               __builtin_bit_cast(bf16x8, a), __builtin_bit_cast(bf16x8, b0), acc0, 0, 0, 0);
      acc1 = __builtin_amdgcn_mfma_f32_16x16x32_bf16(
               __builtin_bit_cast(bf16x8, a), __builtin_bit_cast(bf16x8, b1), acc1, 0, 0, 0);
    }

    // ---- h part (t=0: h is zero, skip). Flag wait + agent-scope loads. ----
    if (t > 0) {
      if (wv == 0) {
        unsigned int* fp = flags + (size_t)(g * WPG + (l & 31)) * 16;
        while (true) {
          unsigned int v = __hip_atomic_load(fp, __ATOMIC_RELAXED, __HIP_MEMORY_SCOPE_AGENT);
          if (__all((int)(v >= (unsigned)t))) break;
          __builtin_amdgcn_s_sleep(1);
        }
      }
      __syncthreads();

      short8 hf[8];
      #pragma unroll
      for (int j = 2; j < 10; ++j) {
        const int kk    = wv + 4 * j;
        const int kbase = kk * 32 + lk - IN_;
        const unsigned short* p = hcur + (size_t)(bb + lrow) * L_ + kbase;
        ld_x4(hf[j - 2], p);
      }
      asm volatile("s_waitcnt vmcnt(0)" ::: "memory");
      __builtin_amdgcn_sched_barrier(0);

      #pragma unroll
      for (int j = 2; j < 10; ++j) {
        const int kbase = (wv + 4 * j) * 32 + lk;
        short8 b0 = *(const short8*)&Wlds[lrow        * PAD_K + kbase];
        short8 b1 = *(const short8*)&Wlds[(lrow + 16) * PAD_K + kbase];
        acc0 = __builtin_amdgcn_mfma_f32_16x16x32_bf16(
                 __builtin_bit_cast(bf16x8, hf[j - 2]), __builtin_bit_cast(bf16x8, b0), acc0, 0, 0, 0);
        acc1 = __builtin_amdgcn_mfma_f32_16x16x32_bf16(
                 __builtin_bit_cast(bf16x8, hf[j - 2]), __builtin_bit_cast(bf16x8, b1), acc1, 0, 0, 0);
      }
    }

    // ---- cross-wave K reduction via LDS ----
    #pragma unroll
    for (int j = 0; j < 4; ++j) {
      red[((wv * 2 + 0) * 4 + j) * 64 + l] = acc0[j];
      red[((wv * 2 + 1) * 4 + j) * 64 + l] = acc1[j];
    }
    __syncthreads();
    if (wv < 2) {
      const int tile = wv;
      #pragma unroll
      for (int j = 0; j < 4; ++j) {
        float s = red[((0 * 2 + tile) * 4 + j) * 64 + l]
                + red[((1 * 2 + tile) * 4 + j) * 64 + l]
                + red[((2 * 2 + tile) * 4 + j) * 64 + l]
                + red[((3 * 2 + tile) * 4 + j) * 64 + l];
        float hv = fast_tanh(s);
        // C/D layout: col = lane&15, row = (lane>>4)*4 + reg
        stile[((l >> 4) * 4 + j) * 32 + tile * 16 + (l & 15)] = f2b(hv);
      }
    }
    __syncthreads();

    // ---- publish tile (agent scope), drain, raise monotonic flag ----
    {
      unsigned int v = ((const unsigned int*)stile)[tid];
      unsigned int* dp = (unsigned int*)(hnxt + (size_t)(bb + (tid >> 4)) * L_ + cc) + (tid & 15);
      st_dw(dp, v);
    }
    asm volatile("s_waitcnt vmcnt(0)" ::: "memory");
    __syncthreads();   // all 4 waves' stores drained before the flag goes up
    if (tid == 0)
      __hip_atomic_store(myflag, (unsigned)(t + 1), __ATOMIC_RELAXED, __HIP_MEMORY_SCOPE_AGENT);
  }
}

__global__ __launch_bounds__(256)
void decode_kernel(const unsigned short* __restrict__ hfin,
                   const float* __restrict__ Wdec, const float* __restrict__ bdec,
                   float* __restrict__ out)
{
  __shared__ float hrow[L_];
  const int b = blockIdx.x, tid = threadIdx.x;
  for (int k = tid; k < L_; k += 256)
    hrow[k] = b2f(hfin[b * L_ + k]);
  __syncthreads();
  float s = bdec[tid];
  const float* wr = Wdec + (size_t)tid * L_;
  #pragma unroll 4
  for (int k = 0; k < L_; k += 4) {
    f32x4 wq = *(const f32x4*)(wr + k);
    s += hrow[k] * wq[0] + hrow[k+1] * wq[1] + hrow[k+2] * wq[2] + hrow[k+3] * wq[3];
  }
  out[b * OUT_ + tid] = fast_tanh(s);
}

extern "C" void kernel_launch(void* const* d_in, const int* in_sizes, int n_in,
                              void* d_out, int out_size, void* d_ws, size_t ws_size,
                              hipStream_t stream)
{
  const float* x    = (const float*)d_in[0];
  const float* Wlin = (const float*)d_in[1];
  const float* Wdec = (const float*)d_in[2];
  const float* bdec = (const float*)d_in[3];
  float* out = (float*)d_out;

  // ws layout: h double buffer (2 x 128x1024 bf16 = 512 KB), then flag array (16 KB).
  unsigned short* h0 = (unsigned short*)d_ws;
  unsigned short* h1 = h0 + (size_t)B_ * L_;
  unsigned int* flags = (unsigned int*)((char*)d_ws + (size_t)2 * B_ * L_ * 2);

  hipMemsetAsync(flags, 0, (size_t)GROUPS * WPG * 16 * sizeof(unsigned int), stream);

  hipFuncSetAttribute((const void*)rnn_persistent,
                      hipFuncAttributeMaxDynamicSharedMemorySize, LDS_TOTAL);

  hipLaunchKernelGGL(rnn_persistent, dim3(GROUPS * WPG), dim3(256), LDS_TOTAL, stream,
                     x, Wlin, h0, h1, flags);
  // final h = output of step 1023, written to buffer parity (1023+1)&1 = 0
  hipLaunchKernelGGL(decode_kernel, dim3(B_), dim3(256), 0, stream,
                     h0, Wdec, bdec, out);
}